// Round 8
// baseline (40.601 us; speedup 1.0000x reference)
//
#include <hip/hip_runtime.h>
#include <math.h>

#define NSLOT 5
#define EPSF 1e-8f

typedef float f4 __attribute__((ext_vector_type(4)));

// ---------------- binning kernels ----------------

__global__ void hist_kernel(const int* __restrict__ labels, int* __restrict__ counts, int B) {
    int i = blockIdx.x * blockDim.x + threadIdx.x;
    if (i < B) atomicAdd(&counts[labels[i]], 1);
}

__global__ void scan_kernel(const int* __restrict__ counts, int* __restrict__ cursor, int C) {
    __shared__ int sh[1024];
    __shared__ int running;
    if (threadIdx.x == 0) running = 0;
    __syncthreads();
    for (int base = 0; base < C; base += 1024) {
        int t = base + threadIdx.x;
        int v = (t < C) ? counts[t] : 0;
        sh[threadIdx.x] = v;
        __syncthreads();
        for (int d = 1; d < 1024; d <<= 1) {
            int x = (threadIdx.x >= d) ? sh[threadIdx.x - d] : 0;
            __syncthreads();
            sh[threadIdx.x] += x;
            __syncthreads();
        }
        int excl = sh[threadIdx.x] - v + running;
        if (t < C) cursor[t] = excl;
        __syncthreads();
        if (threadIdx.x == 0) running += sh[1023];
        __syncthreads();
    }
}

__global__ void scatter_kernel(const int* __restrict__ labels, int* __restrict__ cursor,
                               int* __restrict__ bucket, int B) {
    int i = blockIdx.x * blockDim.x + threadIdx.x;
    if (i < B) {
        int slot = atomicAdd(&cursor[labels[i]], 1);
        bucket[slot] = i;
    }
}

// ---------------- main kernel: 2 waves per sample, 2 samples per block ----------------
// Sorted position j = (b&7)*(B/8) + (b>>3)*2 + sidx  (XCD-contiguous stripes).
// Wave pair {2*sidx, 2*sidx+1} splits the 8 chunks of D=2048 (4 each);
// partial sums combined through LDS (11 floats per wave), epilogue redundant.

__global__ __launch_bounds__(256, 8) void mb_main_kernel(
    const float* __restrict__ query,
    const float* __restrict__ mkeys,
    const float* __restrict__ mvals,
    const float* __restrict__ qscores,
    const int*   __restrict__ topk_p,
    const int*   __restrict__ labels,
    const int*   __restrict__ bucket,   // nullptr -> identity
    float* __restrict__ out_ret,
    float* __restrict__ out_w,
    int B)
{
    const int tid  = threadIdx.x;
    const int lane = tid & 63;
    const int wave = tid >> 6;          // 0..3
    const int ws   = wave & 1;          // half within sample
    const int sidx = wave >> 1;         // sample within block

    int j;
    if (bucket) {
        j = (blockIdx.x & 7) * (B >> 3) + (blockIdx.x >> 3) * 2 + sidx;
    } else {
        j = blockIdx.x * 2 + sidx;
    }
    const bool active = (j < B);
    const int i = active ? (bucket ? bucket[j] : j) : 0;
    const int c = active ? labels[i] : 0;

    int k = topk_p[0];
    if (k > NSLOT) k = NSLOT;
    if (k < 1) k = 1;

    const int n4 = 512;                 // D = 2048
    const f4* q4 = reinterpret_cast<const f4*>(query) + (size_t)i * n4;
    const f4* k4 = reinterpret_cast<const f4*>(mkeys) + (size_t)c * NSLOT * n4;
    const f4* v4 = reinterpret_cast<const f4*>(mvals) + (size_t)c * NSLOT * n4;
    f4*       o4 = reinterpret_cast<f4*>(out_ret) + (size_t)i * n4;

    // ---- pass 1: this wave's 4 chunks ----
    float qq = 0.f;
    float dot[NSLOT], kk[NSLOT];
#pragma unroll
    for (int s = 0; s < NSLOT; ++s) { dot[s] = 0.f; kk[s] = 0.f; }

    if (active) {
#pragma unroll
        for (int m = 0; m < 4; ++m) {
            const int idx = lane + (ws * 4 + m) * 64;
            f4 q = q4[idx];
            qq = fmaf(q.x, q.x, fmaf(q.y, q.y, fmaf(q.z, q.z, fmaf(q.w, q.w, qq))));
#pragma unroll
            for (int s = 0; s < NSLOT; ++s) {
                f4 kv = k4[s * n4 + idx];
                dot[s] = fmaf(q.x, kv.x, fmaf(q.y, kv.y, fmaf(q.z, kv.z, fmaf(q.w, kv.w, dot[s]))));
                kk[s]  = fmaf(kv.x, kv.x, fmaf(kv.y, kv.y, fmaf(kv.z, kv.z, fmaf(kv.w, kv.w, kk[s]))));
            }
        }
    }

    // ---- butterfly reduce within wave ----
#pragma unroll
    for (int off = 1; off < 64; off <<= 1) {
        qq += __shfl_xor(qq, off);
#pragma unroll
        for (int s = 0; s < NSLOT; ++s) {
            dot[s] += __shfl_xor(dot[s], off);
            kk[s]  += __shfl_xor(kk[s], off);
        }
    }

    // ---- cross-wave combine via LDS (11 floats per wave) ----
    __shared__ float red[2][2][11];
    if (lane == 0) {
        red[sidx][ws][0] = qq;
#pragma unroll
        for (int s = 0; s < NSLOT; ++s) {
            red[sidx][ws][1 + s] = dot[s];
            red[sidx][ws][6 + s] = kk[s];
        }
    }
    __syncthreads();
    qq = red[sidx][0][0] + red[sidx][1][0];
#pragma unroll
    for (int s = 0; s < NSLOT; ++s) {
        dot[s] = red[sidx][0][1 + s] + red[sidx][1][1 + s];
        kk[s]  = red[sidx][0][6 + s] + red[sidx][1][6 + s];
    }

    if (!active) return;

    // ---- scalar epilogue (redundant on both waves of the sample) ----
    float qn = fmaxf(sqrtf(qq), EPSF);

    float scr[NSLOT];
    float ssum = 0.f;
#pragma unroll
    for (int s = 0; s < NSLOT; ++s) {
        scr[s] = qscores[(size_t)c * NSLOT + s];
        ssum += scr[s];
    }

    float comb[NSLOT];
#pragma unroll
    for (int s = 0; s < NSLOT; ++s) {
        float kn = fmaxf(sqrtf(kk[s]), EPSF);
        comb[s] = (dot[s] / (qn * kn)) * scr[s];
    }

    // top-k descending; ties -> lowest index
    bool used[NSLOT];
#pragma unroll
    for (int s = 0; s < NSLOT; ++s) used[s] = false;
    float tsc[NSLOT];
    int   tix[NSLOT];
#pragma unroll
    for (int jj = 0; jj < NSLOT; ++jj) {
        float best = -INFINITY;
        int bi = 0;
        if (jj < k) {
#pragma unroll
            for (int s = 0; s < NSLOT; ++s) {
                if (!used[s] && comb[s] > best) { best = comb[s]; bi = s; }
            }
#pragma unroll
            for (int s = 0; s < NSLOT; ++s) used[s] = used[s] || (s == bi);
        }
        tsc[jj] = best;
        tix[jj] = bi;
    }

    const bool hit = (ssum != 0.0f);
    float m = tsc[0];
    float esum = 0.f, wsum = 0.f;
    float a[NSLOT];
#pragma unroll
    for (int jj = 0; jj < NSLOT; ++jj) {
        if (jj < k) {
            a[jj] = __expf((tsc[jj] - m) * 10.0f);   // 1/TEMP = 10
            esum += a[jj];
            wsum += tsc[jj];
        } else {
            a[jj] = 0.f;
        }
    }
    float inv = hit ? (1.0f / esum) : 0.0f;

    if (ws == 0 && lane == 0) out_w[i] = hit ? (wsum / (float)k) : 0.0f;

    // ---- pass 2: this wave's 4 chunks, only selected rows ----
    if (k == 3) {
        const float a0 = a[0] * inv, a1 = a[1] * inv, a2 = a[2] * inv;
        const f4* p0 = v4 + tix[0] * n4;
        const f4* p1 = v4 + tix[1] * n4;
        const f4* p2 = v4 + tix[2] * n4;
#pragma unroll
        for (int m2 = 0; m2 < 4; ++m2) {
            const int idx = lane + (ws * 4 + m2) * 64;
            f4 v0 = p0[idx];
            f4 v1 = p1[idx];
            f4 v2 = p2[idx];
            f4 acc;
            acc.x = fmaf(a0, v0.x, fmaf(a1, v1.x, a2 * v2.x));
            acc.y = fmaf(a0, v0.y, fmaf(a1, v1.y, a2 * v2.y));
            acc.z = fmaf(a0, v0.z, fmaf(a1, v1.z, a2 * v2.z));
            acc.w = fmaf(a0, v0.w, fmaf(a1, v1.w, a2 * v2.w));
            o4[idx] = acc;
        }
    } else {
        float wgt[NSLOT];
#pragma unroll
        for (int s = 0; s < NSLOT; ++s) {
            float wsv = 0.f;
#pragma unroll
            for (int jj = 0; jj < NSLOT; ++jj)
                if (jj < k && tix[jj] == s) wsv += a[jj] * inv;
            wgt[s] = wsv;
        }
#pragma unroll
        for (int m2 = 0; m2 < 4; ++m2) {
            const int idx = lane + (ws * 4 + m2) * 64;
            f4 acc = (f4)(0.f);
#pragma unroll
            for (int s = 0; s < NSLOT; ++s) {
                f4 v = v4[s * n4 + idx];
                acc.x = fmaf(wgt[s], v.x, acc.x);
                acc.y = fmaf(wgt[s], v.y, acc.y);
                acc.z = fmaf(wgt[s], v.z, acc.z);
                acc.w = fmaf(wgt[s], v.w, acc.w);
            }
            o4[idx] = acc;
        }
    }
}

// ---------------- generic fallback (any D), sample-centric ----------------

__global__ __launch_bounds__(64) void mb_generic_kernel(
    const float* __restrict__ query,
    const int*   __restrict__ labels,
    const float* __restrict__ mkeys,
    const float* __restrict__ mvals,
    const float* __restrict__ qscores,
    const int*   __restrict__ topk_p,
    float* __restrict__ out_ret,
    float* __restrict__ out_w,
    int B, int n4)
{
    const int lane = threadIdx.x;
    const int i    = blockIdx.x;
    if (i >= B) return;
    const int c = labels[i];
    int k = topk_p[0];
    if (k > NSLOT) k = NSLOT;
    if (k < 1) k = 1;

    const f4* q4 = reinterpret_cast<const f4*>(query) + (size_t)i * n4;
    const f4* k4 = reinterpret_cast<const f4*>(mkeys) + (size_t)c * NSLOT * n4;
    const f4* v4 = reinterpret_cast<const f4*>(mvals) + (size_t)c * NSLOT * n4;
    f4*       o4 = reinterpret_cast<f4*>(out_ret) + (size_t)i * n4;

    float qq = 0.f, dot[NSLOT] = {0}, kk[NSLOT] = {0};
    for (int idx = lane; idx < n4; idx += 64) {
        f4 q = q4[idx];
        qq = fmaf(q.x, q.x, fmaf(q.y, q.y, fmaf(q.z, q.z, fmaf(q.w, q.w, qq))));
        for (int s = 0; s < NSLOT; ++s) {
            f4 t = k4[s * n4 + idx];
            dot[s] = fmaf(q.x, t.x, fmaf(q.y, t.y, fmaf(q.z, t.z, fmaf(q.w, t.w, dot[s]))));
            kk[s]  = fmaf(t.x, t.x, fmaf(t.y, t.y, fmaf(t.z, t.z, fmaf(t.w, t.w, kk[s]))));
        }
    }
    for (int o = 1; o < 64; o <<= 1) {
        qq += __shfl_xor(qq, o);
        for (int s = 0; s < NSLOT; ++s) {
            dot[s] += __shfl_xor(dot[s], o);
            kk[s]  += __shfl_xor(kk[s], o);
        }
    }
    float qn = fmaxf(sqrtf(qq), EPSF);
    float scr[NSLOT], ssum = 0.f;
    for (int s = 0; s < NSLOT; ++s) { scr[s] = qscores[(size_t)c * NSLOT + s]; ssum += scr[s]; }
    float comb[NSLOT];
    for (int s = 0; s < NSLOT; ++s)
        comb[s] = (dot[s] / (qn * fmaxf(sqrtf(kk[s]), EPSF))) * scr[s];
    bool used[NSLOT] = {false, false, false, false, false};
    float tsc[NSLOT]; int tix[NSLOT];
    for (int jj = 0; jj < NSLOT; ++jj) {
        float best = -INFINITY; int bi = 0;
        if (jj < k) {
            for (int s = 0; s < NSLOT; ++s)
                if (!used[s] && comb[s] > best) { best = comb[s]; bi = s; }
            used[bi] = true;
        }
        tsc[jj] = best; tix[jj] = bi;
    }
    const bool hit = (ssum != 0.0f);
    float m = tsc[0], esum = 0.f, wsum = 0.f, a[NSLOT];
    for (int jj = 0; jj < NSLOT; ++jj) {
        if (jj < k) { a[jj] = __expf((tsc[jj] - m) * 10.0f); esum += a[jj]; wsum += tsc[jj]; }
        else a[jj] = 0.f;
    }
    float inv = hit ? (1.0f / esum) : 0.0f;
    float w[NSLOT];
    for (int s = 0; s < NSLOT; ++s) {
        float wsv = 0.f;
        for (int jj = 0; jj < NSLOT; ++jj) if (jj < k && tix[jj] == s) wsv += a[jj] * inv;
        w[s] = wsv;
    }
    if (lane == 0) out_w[i] = hit ? (wsum / (float)k) : 0.0f;
    for (int idx = lane; idx < n4; idx += 64) {
        f4 acc = (f4)(0.f);
        for (int s = 0; s < NSLOT; ++s) {
            f4 v = v4[s * n4 + idx];
            acc += v * w[s];
        }
        o4[idx] = acc;
    }
}

extern "C" void kernel_launch(void* const* d_in, const int* in_sizes, int n_in,
                              void* d_out, int out_size, void* d_ws, size_t ws_size,
                              hipStream_t stream) {
    const float* query   = (const float*)d_in[0];
    const int*   labels  = (const int*)d_in[1];
    const float* mkeys   = (const float*)d_in[2];
    const float* mvals   = (const float*)d_in[3];
    const float* qscores = (const float*)d_in[4];
    const int*   topk    = (const int*)d_in[5];

    const int B  = in_sizes[1];
    const int D  = in_sizes[0] / B;
    const int n4 = D >> 2;
    const int C  = in_sizes[4] / NSLOT;

    float* out_ret = (float*)d_out;
    float* out_w   = out_ret + (size_t)B * D;

    if (D == 2048 && (B % 16 == 0) &&
        ((size_t)(2 * C + B) * sizeof(int) <= ws_size)) {
        int* counts = (int*)d_ws;
        int* cursor = counts + C;
        int* bkt    = counts + 2 * C;
        hipMemsetAsync(counts, 0, (size_t)C * sizeof(int), stream);
        hist_kernel<<<dim3((B + 255) / 256), dim3(256), 0, stream>>>(labels, counts, B);
        scan_kernel<<<dim3(1), dim3(1024), 0, stream>>>(counts, cursor, C);
        scatter_kernel<<<dim3((B + 255) / 256), dim3(256), 0, stream>>>(labels, cursor, bkt, B);

        mb_main_kernel<<<dim3(B / 2), dim3(256), 0, stream>>>(
            query, mkeys, mvals, qscores, topk, labels, bkt, out_ret, out_w, B);
    } else if (D == 2048) {
        mb_main_kernel<<<dim3((B + 1) / 2), dim3(256), 0, stream>>>(
            query, mkeys, mvals, qscores, topk, labels, nullptr, out_ret, out_w, B);
    } else {
        mb_generic_kernel<<<dim3(B), dim3(64), 0, stream>>>(
            query, labels, mkeys, mvals, qscores, topk, out_ret, out_w, B, n4);
    }
}